// Round 13
// baseline (352.862 us; speedup 1.0000x reference)
//
#include <hip/hip_runtime.h>
#include <hip/hip_bf16.h>

#define N_NODES 50000
#define N_EDGES 800000
#define E_TOT 850000  // edges + self loops, CSR-resident
#define F_IN 32
#define CELL_DIM 16
#define D_IN 48      // F_IN + CELL_DIM
#define X_STRIDE 33  // F_IN + 1 (cell id column)
#define NUM_CELLS 854
#define NEG_SLOPE 0.2f
#define SCAN_BLOCKS 49     // ceil(50000/1024)
#define NODE0_BLOCKS 512   // persistent blocks for k_node0 part
#define HIST_BLOCKS 3125   // ceil(800000/256)

typedef unsigned int uint;
typedef unsigned short ushort;

// f32 -> bf16 bits, round-to-nearest-even
static __device__ __forceinline__ uint f2b(float f) {
  uint x = __float_as_uint(f);
  return (x + 0x7fffu + ((x >> 16) & 1u)) >> 16;
}
static __device__ __forceinline__ float b2f_lo(uint w) { return __uint_as_float(w << 16); }
static __device__ __forceinline__ float b2f_hi(uint w) { return __uint_as_float(w & 0xffff0000u); }
static __device__ __forceinline__ float lrelu(float e) { return e > 0.f ? e : NEG_SLOPE * e; }

// ---------------- Fused node0 (tiled, persistent) + degree histogram ----------------

__global__ __launch_bounds__(256, 4) void k_node0h(const float* __restrict__ x,
                                                   const float* __restrict__ emb,
                                                   const float* __restrict__ W0,
                                                   const float* __restrict__ asrc,
                                                   const float* __restrict__ adst,
                                                   const int* __restrict__ ei,
                                                   uint* __restrict__ h0p,
                                                   float2* __restrict__ as0,
                                                   float2* __restrict__ ad0,
                                                   int* __restrict__ deg) {
  int tid = threadIdx.x;
  if (blockIdx.x >= NODE0_BLOCKS) {  // histogram part
    int e = (blockIdx.x - NODE0_BLOCKS) * 256 + tid;
    if (e < N_EDGES) atomicAdd(&deg[ei[N_EDGES + e]], 1);
    return;
  }
  __shared__ float hin_s[4][4][48];  // [wave][node][k]
  int lane = tid & 63, wid = tid >> 6;
  float2 w0r[D_IN];
#pragma unroll
  for (int k = 0; k < D_IN; ++k)
    w0r[k] = make_float2(W0[k * 128 + lane], W0[k * 128 + 64 + lane]);
  float a_s0 = asrc[lane], a_s1 = asrc[64 + lane];
  float a_d0 = adst[lane], a_d1 = adst[64 + lane];

  int gw = blockIdx.x * 4 + wid;
  for (int g = gw; g < N_NODES / 4; g += NODE0_BLOCKS * 4) {
    int nb = g * 4;
#pragma unroll
    for (int j = 0; j < 4; ++j) {
      int n = nb + j;
      float t = 0.f;
      if (lane < 33) t = x[n * X_STRIDE + lane];
      int cid = (int)__shfl(t, 32, 64);
      cid = cid < 0 ? 0 : (cid >= NUM_CELLS ? NUM_CELLS - 1 : cid);  // fault guard
      if (lane >= 32 && lane < 48) t = emb[cid * CELL_DIM + (lane - 32)];
      if (lane < 48) hin_s[wid][j][lane] = t;
    }
#pragma unroll
    for (int j = 0; j < 4; ++j) {
      int n = nb + j;
      const float4* hp = (const float4*)hin_s[wid][j];
      float acc0 = 0.f, acc1 = 0.f;
#pragma unroll
      for (int k4 = 0; k4 < 12; ++k4) {
        float4 h = hp[k4];
        acc0 = fmaf(h.x, w0r[4 * k4 + 0].x, acc0); acc1 = fmaf(h.x, w0r[4 * k4 + 0].y, acc1);
        acc0 = fmaf(h.y, w0r[4 * k4 + 1].x, acc0); acc1 = fmaf(h.y, w0r[4 * k4 + 1].y, acc1);
        acc0 = fmaf(h.z, w0r[4 * k4 + 2].x, acc0); acc1 = fmaf(h.z, w0r[4 * k4 + 2].y, acc1);
        acc0 = fmaf(h.w, w0r[4 * k4 + 3].x, acc0); acc1 = fmaf(h.w, w0r[4 * k4 + 3].y, acc1);
      }
      h0p[n * 64 + lane] = f2b(acc0) | (f2b(acc1) << 16);
      float sa0 = acc0 * a_s0, sa1 = acc1 * a_s1;
      float sd0 = acc0 * a_d0, sd1 = acc1 * a_d1;
#pragma unroll
      for (int o = 32; o >= 1; o >>= 1) {
        sa0 += __shfl_xor(sa0, o, 64);
        sa1 += __shfl_xor(sa1, o, 64);
        sd0 += __shfl_xor(sd0, o, 64);
        sd1 += __shfl_xor(sd1, o, 64);
      }
      if (lane == 0) {
        as0[n] = make_float2(sa0, sa1);
        ad0[n] = make_float2(sd0, sd1);
      }
    }
  }
}

// ---------------- CSR scans ----------------

__global__ __launch_bounds__(1024) void k_scan1(const int* __restrict__ deg, int* __restrict__ off,
                                                int* __restrict__ bsum) {
  __shared__ int ws[16];
  int tid = threadIdx.x;
  int lane = tid & 63, wid = tid >> 6;
  int i = blockIdx.x * 1024 + tid;
  int v = (i < N_NODES) ? deg[i] + 1 : 0;  // +1 slot for self-loop
  int sc = v;
#pragma unroll
  for (int o = 1; o < 64; o <<= 1) {
    int t = __shfl_up(sc, o, 64);
    if (lane >= o) sc += t;
  }
  if (lane == 63) ws[wid] = sc;
  __syncthreads();
  if (tid < 16) {
    int w = ws[tid];
    int s = w;
#pragma unroll
    for (int o = 1; o < 16; o <<= 1) {
      int t = __shfl_up(s, o, 64);
      if (tid >= o) s += t;
    }
    ws[tid] = s - w;  // exclusive wave prefix
  }
  __syncthreads();
  int excl = sc - v + ws[wid];
  if (i < N_NODES) off[i] = excl;
  if (tid == 1023) bsum[blockIdx.x] = excl + v;  // block total
}

__global__ __launch_bounds__(1024) void k_scan23(int* __restrict__ off, int* __restrict__ ofs,
                                                 const int* __restrict__ bsum) {
  __shared__ int carry_s;
  int tid = threadIdx.x;
  if (tid < 64) {
    int v = (tid < SCAN_BLOCKS) ? bsum[tid] : 0;
    int s = v;
#pragma unroll
    for (int o = 1; o < 64; o <<= 1) {
      int t = __shfl_up(s, o, 64);
      if (tid >= o) s += t;
    }
    if (tid == (int)blockIdx.x) carry_s = s - v;  // exclusive prefix of this block
  }
  __syncthreads();
  int carry = carry_s;
  int i = blockIdx.x * 1024 + tid;
  if (i < N_NODES) {
    int v = off[i] + carry;
    off[i] = v;
    ofs[i] = v;
  }
  if (i == 0) off[N_NODES] = E_TOT;
}

// scatter edges into CSR slots + compute layer-0 attention weights; tail fills self-loops
__global__ __launch_bounds__(256) void k_scatter(const int* __restrict__ ei, int* __restrict__ ofs,
                                                 const int* __restrict__ off,
                                                 const float2* __restrict__ as0v,
                                                 const float2* __restrict__ ad0v,
                                                 uint2* __restrict__ ew) {
  int t = blockIdx.x * 256 + threadIdx.x;
  if (t < N_EDGES) {
    int s = ei[t], d = ei[N_EDGES + t];
    float2 a_s = as0v[s], a_d = ad0v[d];
    float w0 = __expf(lrelu(a_s.x + a_d.x));
    float w1 = __expf(lrelu(a_s.y + a_d.y));
    int p = atomicAdd(&ofs[d], 1);
    ew[p] = make_uint2((uint)s, f2b(w0) | (f2b(w1) << 16));
  } else if (t < N_EDGES + N_NODES) {
    int n = t - N_EDGES;  // self-loop record in the reserved last slot
    int slot = off[n + 1] - 1;
    float2 a_s = as0v[n], a_d = ad0v[n];
    float w0 = __expf(lrelu(a_s.x + a_d.x));
    float w1 = __expf(lrelu(a_s.y + a_d.y));
    ew[slot] = make_uint2((uint)n, f2b(w0) | (f2b(w1) << 16));
  }
}

// ---------------- agg0 epilogue: mean-heads + bias + LN + ELU + linear1 + alpha1 ----------------

static __device__ __forceinline__ void epi0(int n, int lane, float acc0, float acc1, float den0,
                                            float den1, const float* __restrict__ b0,
                                            const float* __restrict__ lng,
                                            const float* __restrict__ lnb,
                                            const float* __restrict__ W1,
                                            const float* __restrict__ asrc1,
                                            const float* __restrict__ adst1,
                                            ushort* __restrict__ h1b, float* __restrict__ as1,
                                            float* __restrict__ ad1) {
  float v = 0.5f * (acc0 / den0 + acc1 / den1) + b0[lane];
  float mu = v;
#pragma unroll
  for (int o = 32; o >= 1; o >>= 1) mu += __shfl_xor(mu, o, 64);
  mu *= (1.0f / 64.0f);
  float d = v - mu;
  float vr = d * d;
#pragma unroll
  for (int o = 32; o >= 1; o >>= 1) vr += __shfl_xor(vr, o, 64);
  vr *= (1.0f / 64.0f);
  float y = d * rsqrtf(vr + 1e-5f) * lng[lane] + lnb[lane];
  y = y > 0.f ? y : expm1f(y);
  float h1v = 0.f;
#pragma unroll
  for (int k = 0; k < 64; ++k) {
    float yk = __shfl(y, k, 64);
    h1v += yk * W1[k * 64 + lane];
  }
  h1b[n * 64 + lane] = (ushort)f2b(h1v);
  float sa = h1v * asrc1[lane];
  float sdv = h1v * adst1[lane];
#pragma unroll
  for (int o = 32; o >= 1; o >>= 1) {
    sa += __shfl_xor(sa, o, 64);
    sdv += __shfl_xor(sdv, o, 64);
  }
  if (lane == 0) {
    as1[n] = sa;
    ad1[n] = sdv;
  }
}

// ---------------- Fused aggregate L0: TWO independent edge streams per wave ----------------
// Wave owns nodes A,B; loop processes 2 edges of each per iteration (4 independent gathers,
// no shfl, no LDS, full-length streams). Block = 4 waves = 8 nodes.

__global__ __launch_bounds__(256) void k_agg0(const int* __restrict__ off,
                                              const uint2* __restrict__ ew,
                                              const uint* __restrict__ h0p,
                                              const float* __restrict__ b0,
                                              const float* __restrict__ lng,
                                              const float* __restrict__ lnb,
                                              const float* __restrict__ W1,
                                              const float* __restrict__ asrc1,
                                              const float* __restrict__ adst1,
                                              ushort* __restrict__ h1b,
                                              float* __restrict__ as1, float* __restrict__ ad1) {
  int lane = threadIdx.x & 63;
  int nA = blockIdx.x * 8 + (threadIdx.x >> 6) * 2;
  int nB = nA + 1;
  int a0 = off[nA], a1 = off[nA + 1];
  int b0i = off[nB], b1i = off[nB + 1];
  int cA = a1 - a0, cB = b1i - b0i;
  int m = cA < cB ? cA : cB;
  float accA0 = 0.f, accA1 = 0.f, denA0 = 0.f, denA1 = 0.f;
  float accB0 = 0.f, accB1 = 0.f, denB0 = 0.f, denB1 = 0.f;
  int j = 0;
  for (; j + 1 < m; j += 2) {
    uint2 rA0 = ew[a0 + j], rA1 = ew[a0 + j + 1];
    uint2 rB0 = ew[b0i + j], rB1 = ew[b0i + j + 1];
    uint hA0 = h0p[rA0.x * 64 + lane];
    uint hA1 = h0p[rA1.x * 64 + lane];
    uint hB0 = h0p[rB0.x * 64 + lane];
    uint hB1 = h0p[rB1.x * 64 + lane];
    float w;
    w = b2f_lo(rA0.y); accA0 += w * b2f_lo(hA0); denA0 += w;
    w = b2f_hi(rA0.y); accA1 += w * b2f_hi(hA0); denA1 += w;
    w = b2f_lo(rA1.y); accA0 += w * b2f_lo(hA1); denA0 += w;
    w = b2f_hi(rA1.y); accA1 += w * b2f_hi(hA1); denA1 += w;
    w = b2f_lo(rB0.y); accB0 += w * b2f_lo(hB0); denB0 += w;
    w = b2f_hi(rB0.y); accB1 += w * b2f_hi(hB0); denB1 += w;
    w = b2f_lo(rB1.y); accB0 += w * b2f_lo(hB1); denB0 += w;
    w = b2f_hi(rB1.y); accB1 += w * b2f_hi(hB1); denB1 += w;
  }
  for (; j < m; ++j) {
    uint2 rA = ew[a0 + j];
    uint2 rB = ew[b0i + j];
    uint hA = h0p[rA.x * 64 + lane];
    uint hB = h0p[rB.x * 64 + lane];
    float w;
    w = b2f_lo(rA.y); accA0 += w * b2f_lo(hA); denA0 += w;
    w = b2f_hi(rA.y); accA1 += w * b2f_hi(hA); denA1 += w;
    w = b2f_lo(rB.y); accB0 += w * b2f_lo(hB); denB0 += w;
    w = b2f_hi(rB.y); accB1 += w * b2f_hi(hB); denB1 += w;
  }
  for (int i = a0 + m; i < a1; ++i) {  // tail of stream A
    uint2 r = ew[i];
    uint h = h0p[r.x * 64 + lane];
    float w;
    w = b2f_lo(r.y); accA0 += w * b2f_lo(h); denA0 += w;
    w = b2f_hi(r.y); accA1 += w * b2f_hi(h); denA1 += w;
  }
  for (int i = b0i + m; i < b1i; ++i) {  // tail of stream B
    uint2 r = ew[i];
    uint h = h0p[r.x * 64 + lane];
    float w;
    w = b2f_lo(r.y); accB0 += w * b2f_lo(h); denB0 += w;
    w = b2f_hi(r.y); accB1 += w * b2f_hi(h); denB1 += w;
  }
  epi0(nA, lane, accA0, accA1, denA0, denA1, b0, lng, lnb, W1, asrc1, adst1, h1b, as1, ad1);
  epi0(nB, lane, accB0, accB1, denB0, denB1, b0, lng, lnb, W1, asrc1, adst1, h1b, as1, ad1);
}

// ---------------- Layer 1 aggregate -> output: two streams per wave, weights inline ----------------

__global__ __launch_bounds__(256) void k_agg1(const int* __restrict__ off,
                                              const uint2* __restrict__ ew,
                                              const ushort* __restrict__ h1b,
                                              const float* __restrict__ as1,
                                              const float* __restrict__ ad1,
                                              const float* __restrict__ b1,
                                              float* __restrict__ out) {
  int lane = threadIdx.x & 63;
  int nA = blockIdx.x * 8 + (threadIdx.x >> 6) * 2;
  int nB = nA + 1;
  float advA = ad1[nA], advB = ad1[nB];
  int a0 = off[nA], a1 = off[nA + 1];
  int b0i = off[nB], b1i = off[nB + 1];
  int cA = a1 - a0, cB = b1i - b0i;
  int m = cA < cB ? cA : cB;
  float accA = 0.f, denA = 0.f, accB = 0.f, denB = 0.f;
  int j = 0;
  for (; j + 1 < m; j += 2) {
    uint sA0 = ew[a0 + j].x, sA1 = ew[a0 + j + 1].x;
    uint sB0 = ew[b0i + j].x, sB1 = ew[b0i + j + 1].x;
    float wA0 = __expf(lrelu(as1[sA0] + advA));
    float wA1 = __expf(lrelu(as1[sA1] + advA));
    float wB0 = __expf(lrelu(as1[sB0] + advB));
    float wB1 = __expf(lrelu(as1[sB1] + advB));
    uint hA0 = h1b[sA0 * 64 + lane];
    uint hA1 = h1b[sA1 * 64 + lane];
    uint hB0 = h1b[sB0 * 64 + lane];
    uint hB1 = h1b[sB1 * 64 + lane];
    accA += wA0 * __uint_as_float(hA0 << 16); denA += wA0;
    accA += wA1 * __uint_as_float(hA1 << 16); denA += wA1;
    accB += wB0 * __uint_as_float(hB0 << 16); denB += wB0;
    accB += wB1 * __uint_as_float(hB1 << 16); denB += wB1;
  }
  for (; j < m; ++j) {
    uint sA = ew[a0 + j].x, sB = ew[b0i + j].x;
    float wA = __expf(lrelu(as1[sA] + advA));
    float wB = __expf(lrelu(as1[sB] + advB));
    accA += wA * __uint_as_float((uint)h1b[sA * 64 + lane] << 16); denA += wA;
    accB += wB * __uint_as_float((uint)h1b[sB * 64 + lane] << 16); denB += wB;
  }
  for (int i = a0 + m; i < a1; ++i) {
    uint s = ew[i].x;
    float w = __expf(lrelu(as1[s] + advA));
    accA += w * __uint_as_float((uint)h1b[s * 64 + lane] << 16);
    denA += w;
  }
  for (int i = b0i + m; i < b1i; ++i) {
    uint s = ew[i].x;
    float w = __expf(lrelu(as1[s] + advB));
    accB += w * __uint_as_float((uint)h1b[s * 64 + lane] << 16);
    denB += w;
  }
  out[nA * 64 + lane] = accA / denA + b1[lane];
  out[nB * 64 + lane] = accB / denB + b1[lane];
}

// ---------------- host ----------------

extern "C" void kernel_launch(void* const* d_in, const int* in_sizes, int n_in,
                              void* d_out, int out_size, void* d_ws, size_t ws_size,
                              hipStream_t stream) {
  const float* x    = (const float*)d_in[0];
  const int*   ei   = (const int*)d_in[1];
  const float* emb  = (const float*)d_in[2];
  const float* W0   = (const float*)d_in[3];
  const float* as0w = (const float*)d_in[4];
  const float* ad0w = (const float*)d_in[5];
  const float* b0   = (const float*)d_in[6];
  const float* lng  = (const float*)d_in[7];
  const float* lnb  = (const float*)d_in[8];
  const float* W1   = (const float*)d_in[9];
  const float* as1w = (const float*)d_in[10];
  const float* ad1w = (const float*)d_in[11];
  const float* b1   = (const float*)d_in[12];
  float* out = (float*)d_out;

  // workspace layout (8B-aligned arrays first); total ~29 MB
  uint2* ew  = (uint2*)d_ws;                  // E_TOT {src, bf16x2 w0|w1}
  float* as0 = (float*)(ew + E_TOT);          // N*2
  float* ad0 = as0 + N_NODES * 2;             // N*2
  float* as1 = ad0 + N_NODES * 2;             // N
  float* ad1 = as1 + N_NODES;                 // N
  uint* h0p = (uint*)(ad1 + N_NODES);         // N*64 (bf16x2 packed)
  ushort* h1b = (ushort*)(h0p + N_NODES * 64);  // N*64 bf16
  int* deg  = (int*)(h1b + N_NODES * 64);     // N
  int* off  = deg + N_NODES;                  // N+1
  int* ofs  = off + N_NODES + 1;              // N
  int* bsum = ofs + N_NODES;                  // 64

  hipMemsetAsync(deg, 0, N_NODES * sizeof(int), stream);
  k_node0h<<<NODE0_BLOCKS + HIST_BLOCKS, 256, 0, stream>>>(x, emb, W0, as0w, ad0w, ei, h0p,
                                                           (float2*)as0, (float2*)ad0, deg);
  k_scan1<<<SCAN_BLOCKS, 1024, 0, stream>>>(deg, off, bsum);
  k_scan23<<<SCAN_BLOCKS, 1024, 0, stream>>>(off, ofs, bsum);
  k_scatter<<<(N_EDGES + N_NODES + 255) / 256, 256, 0, stream>>>(ei, ofs, off, (const float2*)as0,
                                                                 (const float2*)ad0, ew);
  k_agg0<<<N_NODES / 8, 256, 0, stream>>>(off, ew, h0p, b0, lng, lnb, W1, as1w, ad1w,
                                          h1b, as1, ad1);
  k_agg1<<<N_NODES / 8, 256, 0, stream>>>(off, ew, h1b, as1, ad1, b1, out);
}

// Round 14
// 295.710 us; speedup vs baseline: 1.1933x; 1.1933x over previous
//
#include <hip/hip_runtime.h>
#include <hip/hip_bf16.h>

#define N_NODES 50000
#define N_EDGES 800000
#define E_TOT 850000  // edges + self loops, CSR-resident
#define F_IN 32
#define CELL_DIM 16
#define D_IN 48      // F_IN + CELL_DIM
#define X_STRIDE 33  // F_IN + 1 (cell id column)
#define NUM_CELLS 854
#define NEG_SLOPE 0.2f
#define SCAN_BLOCKS 49     // ceil(50000/1024)
#define NODE0_BLOCKS 512   // persistent blocks for k_node0 part
#define HIST_BLOCKS 3125   // ceil(800000/256)

typedef unsigned int uint;
typedef unsigned short ushort;

// f32 -> bf16 bits, round-to-nearest-even
static __device__ __forceinline__ uint f2b(float f) {
  uint x = __float_as_uint(f);
  return (x + 0x7fffu + ((x >> 16) & 1u)) >> 16;
}
static __device__ __forceinline__ float b2f_lo(uint w) { return __uint_as_float(w << 16); }
static __device__ __forceinline__ float b2f_hi(uint w) { return __uint_as_float(w & 0xffff0000u); }
static __device__ __forceinline__ float lrelu(float e) { return e > 0.f ? e : NEG_SLOPE * e; }

// ---------------- Fused node0 (tiled, persistent) + degree histogram ----------------

__global__ __launch_bounds__(256, 4) void k_node0h(const float* __restrict__ x,
                                                   const float* __restrict__ emb,
                                                   const float* __restrict__ W0,
                                                   const float* __restrict__ asrc,
                                                   const float* __restrict__ adst,
                                                   const int* __restrict__ ei,
                                                   uint* __restrict__ h0p,
                                                   float2* __restrict__ as0,
                                                   float2* __restrict__ ad0,
                                                   int* __restrict__ deg) {
  int tid = threadIdx.x;
  if (blockIdx.x >= NODE0_BLOCKS) {  // histogram part
    int e = (blockIdx.x - NODE0_BLOCKS) * 256 + tid;
    if (e < N_EDGES) atomicAdd(&deg[ei[N_EDGES + e]], 1);
    return;
  }
  __shared__ float hin_s[4][4][48];  // [wave][node][k]
  int lane = tid & 63, wid = tid >> 6;
  float2 w0r[D_IN];
#pragma unroll
  for (int k = 0; k < D_IN; ++k)
    w0r[k] = make_float2(W0[k * 128 + lane], W0[k * 128 + 64 + lane]);
  float a_s0 = asrc[lane], a_s1 = asrc[64 + lane];
  float a_d0 = adst[lane], a_d1 = adst[64 + lane];

  int gw = blockIdx.x * 4 + wid;
  for (int g = gw; g < N_NODES / 4; g += NODE0_BLOCKS * 4) {
    int nb = g * 4;
#pragma unroll
    for (int j = 0; j < 4; ++j) {
      int n = nb + j;
      float t = 0.f;
      if (lane < 33) t = x[n * X_STRIDE + lane];
      int cid = (int)__shfl(t, 32, 64);
      cid = cid < 0 ? 0 : (cid >= NUM_CELLS ? NUM_CELLS - 1 : cid);  // fault guard
      if (lane >= 32 && lane < 48) t = emb[cid * CELL_DIM + (lane - 32)];
      if (lane < 48) hin_s[wid][j][lane] = t;
    }
#pragma unroll
    for (int j = 0; j < 4; ++j) {
      int n = nb + j;
      const float4* hp = (const float4*)hin_s[wid][j];
      float acc0 = 0.f, acc1 = 0.f;
#pragma unroll
      for (int k4 = 0; k4 < 12; ++k4) {
        float4 h = hp[k4];
        acc0 = fmaf(h.x, w0r[4 * k4 + 0].x, acc0); acc1 = fmaf(h.x, w0r[4 * k4 + 0].y, acc1);
        acc0 = fmaf(h.y, w0r[4 * k4 + 1].x, acc0); acc1 = fmaf(h.y, w0r[4 * k4 + 1].y, acc1);
        acc0 = fmaf(h.z, w0r[4 * k4 + 2].x, acc0); acc1 = fmaf(h.z, w0r[4 * k4 + 2].y, acc1);
        acc0 = fmaf(h.w, w0r[4 * k4 + 3].x, acc0); acc1 = fmaf(h.w, w0r[4 * k4 + 3].y, acc1);
      }
      h0p[n * 64 + lane] = f2b(acc0) | (f2b(acc1) << 16);
      float sa0 = acc0 * a_s0, sa1 = acc1 * a_s1;
      float sd0 = acc0 * a_d0, sd1 = acc1 * a_d1;
#pragma unroll
      for (int o = 32; o >= 1; o >>= 1) {
        sa0 += __shfl_xor(sa0, o, 64);
        sa1 += __shfl_xor(sa1, o, 64);
        sd0 += __shfl_xor(sd0, o, 64);
        sd1 += __shfl_xor(sd1, o, 64);
      }
      if (lane == 0) {
        as0[n] = make_float2(sa0, sa1);
        ad0[n] = make_float2(sd0, sd1);
      }
    }
  }
}

// ---------------- CSR scans ----------------

__global__ __launch_bounds__(1024) void k_scan1(const int* __restrict__ deg, int* __restrict__ off,
                                                int* __restrict__ bsum) {
  __shared__ int ws[16];
  int tid = threadIdx.x;
  int lane = tid & 63, wid = tid >> 6;
  int i = blockIdx.x * 1024 + tid;
  int v = (i < N_NODES) ? deg[i] + 1 : 0;  // +1 slot for self-loop
  int sc = v;
#pragma unroll
  for (int o = 1; o < 64; o <<= 1) {
    int t = __shfl_up(sc, o, 64);
    if (lane >= o) sc += t;
  }
  if (lane == 63) ws[wid] = sc;
  __syncthreads();
  if (tid < 16) {
    int w = ws[tid];
    int s = w;
#pragma unroll
    for (int o = 1; o < 16; o <<= 1) {
      int t = __shfl_up(s, o, 64);
      if (tid >= o) s += t;
    }
    ws[tid] = s - w;  // exclusive wave prefix
  }
  __syncthreads();
  int excl = sc - v + ws[wid];
  if (i < N_NODES) off[i] = excl;
  if (tid == 1023) bsum[blockIdx.x] = excl + v;  // block total
}

__global__ __launch_bounds__(1024) void k_scan23(int* __restrict__ off, int* __restrict__ ofs,
                                                 const int* __restrict__ bsum) {
  __shared__ int carry_s;
  int tid = threadIdx.x;
  if (tid < 64) {
    int v = (tid < SCAN_BLOCKS) ? bsum[tid] : 0;
    int s = v;
#pragma unroll
    for (int o = 1; o < 64; o <<= 1) {
      int t = __shfl_up(s, o, 64);
      if (tid >= o) s += t;
    }
    if (tid == (int)blockIdx.x) carry_s = s - v;  // exclusive prefix of this block
  }
  __syncthreads();
  int carry = carry_s;
  int i = blockIdx.x * 1024 + tid;
  if (i < N_NODES) {
    int v = off[i] + carry;
    off[i] = v;
    ofs[i] = v;
  }
  if (i == 0) off[N_NODES] = E_TOT;
}

// scatter edges into CSR slots + compute layer-0 attention weights; tail fills self-loops
__global__ __launch_bounds__(256) void k_scatter(const int* __restrict__ ei, int* __restrict__ ofs,
                                                 const int* __restrict__ off,
                                                 const float2* __restrict__ as0v,
                                                 const float2* __restrict__ ad0v,
                                                 uint2* __restrict__ ew) {
  int t = blockIdx.x * 256 + threadIdx.x;
  if (t < N_EDGES) {
    int s = ei[t], d = ei[N_EDGES + t];
    float2 a_s = as0v[s], a_d = ad0v[d];
    float w0 = __expf(lrelu(a_s.x + a_d.x));
    float w1 = __expf(lrelu(a_s.y + a_d.y));
    int p = atomicAdd(&ofs[d], 1);
    ew[p] = make_uint2((uint)s, f2b(w0) | (f2b(w1) << 16));
  } else if (t < N_EDGES + N_NODES) {
    int n = t - N_EDGES;  // self-loop record in the reserved last slot
    int slot = off[n + 1] - 1;
    float2 a_s = as0v[n], a_d = ad0v[n];
    float w0 = __expf(lrelu(a_s.x + a_d.x));
    float w1 = __expf(lrelu(a_s.y + a_d.y));
    ew[slot] = make_uint2((uint)n, f2b(w0) | (f2b(w1) << 16));
  }
}

// ---------------- Fused aggregate L0 (+LN+ELU+linear1+alpha1) ----------------
// One wave per node. Edge records staged per 64-chunk into wave-private LDS with one
// coalesced load; loop reads them back via uniform ds_read (sequential addresses,
// prefetchable) so gather addresses never wait on serial global loads.

__global__ __launch_bounds__(256) void k_agg0(const int* __restrict__ off,
                                              const uint2* __restrict__ ew,
                                              const uint* __restrict__ h0p,
                                              const float* __restrict__ b0,
                                              const float* __restrict__ lng,
                                              const float* __restrict__ lnb,
                                              const float* __restrict__ W1,
                                              const float* __restrict__ asrc1,
                                              const float* __restrict__ adst1,
                                              ushort* __restrict__ h1b,
                                              float* __restrict__ as1, float* __restrict__ ad1) {
  __shared__ uint2 est[4][64];
  int wid = threadIdx.x >> 6;
  int lane = threadIdx.x & 63;
  int n = blockIdx.x * 4 + wid;
  int i0 = off[n], i1 = off[n + 1];
  float acc0 = 0.f, acc1 = 0.f, den0 = 0.f, den1 = 0.f;
  for (int base = i0; base < i1; base += 64) {
    int cnt = i1 - base;
    cnt = cnt < 64 ? cnt : 64;
    if (lane < cnt) est[wid][lane] = ew[base + lane];  // wave-private: no barrier
    int j = 0;
    for (; j + 3 < cnt; j += 4) {
      uint2 r0 = est[wid][j], r1 = est[wid][j + 1];
      uint2 r2 = est[wid][j + 2], r3 = est[wid][j + 3];
      uint h0 = h0p[r0.x * 64 + lane];
      uint h1 = h0p[r1.x * 64 + lane];
      uint h2 = h0p[r2.x * 64 + lane];
      uint h3 = h0p[r3.x * 64 + lane];
      float w;
      w = b2f_lo(r0.y); acc0 += w * b2f_lo(h0); den0 += w;
      w = b2f_hi(r0.y); acc1 += w * b2f_hi(h0); den1 += w;
      w = b2f_lo(r1.y); acc0 += w * b2f_lo(h1); den0 += w;
      w = b2f_hi(r1.y); acc1 += w * b2f_hi(h1); den1 += w;
      w = b2f_lo(r2.y); acc0 += w * b2f_lo(h2); den0 += w;
      w = b2f_hi(r2.y); acc1 += w * b2f_hi(h2); den1 += w;
      w = b2f_lo(r3.y); acc0 += w * b2f_lo(h3); den0 += w;
      w = b2f_hi(r3.y); acc1 += w * b2f_hi(h3); den1 += w;
    }
    for (; j < cnt; ++j) {
      uint2 r = est[wid][j];
      uint h = h0p[r.x * 64 + lane];
      float w;
      w = b2f_lo(r.y); acc0 += w * b2f_lo(h); den0 += w;
      w = b2f_hi(r.y); acc1 += w * b2f_hi(h); den1 += w;
    }
  }
  float v = 0.5f * (acc0 / den0 + acc1 / den1) + b0[lane];
  // LayerNorm across 64 channels
  float mu = v;
#pragma unroll
  for (int o = 32; o >= 1; o >>= 1) mu += __shfl_xor(mu, o, 64);
  mu *= (1.0f / 64.0f);
  float d = v - mu;
  float vr = d * d;
#pragma unroll
  for (int o = 32; o >= 1; o >>= 1) vr += __shfl_xor(vr, o, 64);
  vr *= (1.0f / 64.0f);
  float y = d * rsqrtf(vr + 1e-5f) * lng[lane] + lnb[lane];
  y = y > 0.f ? y : expm1f(y);
  float h1v = 0.f;
#pragma unroll
  for (int k = 0; k < 64; ++k) {
    float yk = __shfl(y, k, 64);
    h1v += yk * W1[k * 64 + lane];
  }
  h1b[n * 64 + lane] = (ushort)f2b(h1v);
  float sa = h1v * asrc1[lane];
  float sdv = h1v * adst1[lane];
#pragma unroll
  for (int o = 32; o >= 1; o >>= 1) {
    sa += __shfl_xor(sa, o, 64);
    sdv += __shfl_xor(sdv, o, 64);
  }
  if (lane == 0) {
    as1[n] = sa;
    ad1[n] = sdv;
  }
}

// ---------------- Layer 1 aggregate -> output (LDS-staged records, weights inline) ----------------

__global__ __launch_bounds__(256) void k_agg1(const int* __restrict__ off,
                                              const uint2* __restrict__ ew,
                                              const ushort* __restrict__ h1b,
                                              const float* __restrict__ as1,
                                              const float* __restrict__ ad1,
                                              const float* __restrict__ b1,
                                              float* __restrict__ out) {
  __shared__ uint est[4][64];
  int wid = threadIdx.x >> 6;
  int lane = threadIdx.x & 63;
  int n = blockIdx.x * 4 + wid;
  float adv = ad1[n];
  int i0 = off[n], i1 = off[n + 1];
  float acc = 0.f, den = 0.f;
  for (int base = i0; base < i1; base += 64) {
    int cnt = i1 - base;
    cnt = cnt < 64 ? cnt : 64;
    if (lane < cnt) est[wid][lane] = ew[base + lane].x;  // wave-private: no barrier
    int j = 0;
    for (; j + 3 < cnt; j += 4) {
      uint s0 = est[wid][j], s1 = est[wid][j + 1];
      uint s2 = est[wid][j + 2], s3 = est[wid][j + 3];
      float w0 = __expf(lrelu(as1[s0] + adv));
      float w1 = __expf(lrelu(as1[s1] + adv));
      float w2 = __expf(lrelu(as1[s2] + adv));
      float w3 = __expf(lrelu(as1[s3] + adv));
      uint h0 = h1b[s0 * 64 + lane];
      uint h1 = h1b[s1 * 64 + lane];
      uint h2 = h1b[s2 * 64 + lane];
      uint h3 = h1b[s3 * 64 + lane];
      acc += w0 * __uint_as_float(h0 << 16); den += w0;
      acc += w1 * __uint_as_float(h1 << 16); den += w1;
      acc += w2 * __uint_as_float(h2 << 16); den += w2;
      acc += w3 * __uint_as_float(h3 << 16); den += w3;
    }
    for (; j < cnt; ++j) {
      uint s = est[wid][j];
      float w = __expf(lrelu(as1[s] + adv));
      acc += w * __uint_as_float((uint)h1b[s * 64 + lane] << 16);
      den += w;
    }
  }
  out[n * 64 + lane] = acc / den + b1[lane];
}

// ---------------- host ----------------

extern "C" void kernel_launch(void* const* d_in, const int* in_sizes, int n_in,
                              void* d_out, int out_size, void* d_ws, size_t ws_size,
                              hipStream_t stream) {
  const float* x    = (const float*)d_in[0];
  const int*   ei   = (const int*)d_in[1];
  const float* emb  = (const float*)d_in[2];
  const float* W0   = (const float*)d_in[3];
  const float* as0w = (const float*)d_in[4];
  const float* ad0w = (const float*)d_in[5];
  const float* b0   = (const float*)d_in[6];
  const float* lng  = (const float*)d_in[7];
  const float* lnb  = (const float*)d_in[8];
  const float* W1   = (const float*)d_in[9];
  const float* as1w = (const float*)d_in[10];
  const float* ad1w = (const float*)d_in[11];
  const float* b1   = (const float*)d_in[12];
  float* out = (float*)d_out;

  // workspace layout (8B-aligned arrays first); total ~29 MB
  uint2* ew  = (uint2*)d_ws;                  // E_TOT {src, bf16x2 w0|w1}
  float* as0 = (float*)(ew + E_TOT);          // N*2
  float* ad0 = as0 + N_NODES * 2;             // N*2
  float* as1 = ad0 + N_NODES * 2;             // N
  float* ad1 = as1 + N_NODES;                 // N
  uint* h0p = (uint*)(ad1 + N_NODES);         // N*64 (bf16x2 packed)
  ushort* h1b = (ushort*)(h0p + N_NODES * 64);  // N*64 bf16
  int* deg  = (int*)(h1b + N_NODES * 64);     // N
  int* off  = deg + N_NODES;                  // N+1
  int* ofs  = off + N_NODES + 1;              // N
  int* bsum = ofs + N_NODES;                  // 64

  hipMemsetAsync(deg, 0, N_NODES * sizeof(int), stream);
  k_node0h<<<NODE0_BLOCKS + HIST_BLOCKS, 256, 0, stream>>>(x, emb, W0, as0w, ad0w, ei, h0p,
                                                           (float2*)as0, (float2*)ad0, deg);
  k_scan1<<<SCAN_BLOCKS, 1024, 0, stream>>>(deg, off, bsum);
  k_scan23<<<SCAN_BLOCKS, 1024, 0, stream>>>(off, ofs, bsum);
  k_scatter<<<(N_EDGES + N_NODES + 255) / 256, 256, 0, stream>>>(ei, ofs, off, (const float2*)as0,
                                                                 (const float2*)ad0, ew);
  k_agg0<<<N_NODES / 4, 256, 0, stream>>>(off, ew, h0p, b0, lng, lnb, W1, as1w, ad1w,
                                          h1b, as1, ad1);
  k_agg1<<<N_NODES / 4, 256, 0, stream>>>(off, ew, h1b, as1, ad1, b1, out);
}

// Round 15
// 280.080 us; speedup vs baseline: 1.2599x; 1.0558x over previous
//
#include <hip/hip_runtime.h>
#include <hip/hip_bf16.h>

#define N_NODES 50000
#define N_EDGES 800000
#define E_TOT 850000  // edges + self loops, CSR-resident
#define F_IN 32
#define CELL_DIM 16
#define D_IN 48      // F_IN + CELL_DIM
#define X_STRIDE 33  // F_IN + 1 (cell id column)
#define NUM_CELLS 854
#define NEG_SLOPE 0.2f
#define SCAN_BLOCKS 49     // ceil(50000/1024)
#define NODE0_BLOCKS 2048  // 8 blocks/CU for the node0 part (was 512 -> 26% occupancy)
#define HIST_BLOCKS 3125   // ceil(800000/256)

typedef unsigned int uint;
typedef unsigned short ushort;

// f32 -> bf16 bits, round-to-nearest-even
static __device__ __forceinline__ uint f2b(float f) {
  uint x = __float_as_uint(f);
  return (x + 0x7fffu + ((x >> 16) & 1u)) >> 16;
}
static __device__ __forceinline__ float b2f_lo(uint w) { return __uint_as_float(w << 16); }
static __device__ __forceinline__ float b2f_hi(uint w) { return __uint_as_float(w & 0xffff0000u); }
static __device__ __forceinline__ float lrelu(float e) { return e > 0.f ? e : NEG_SLOPE * e; }

// ---------------- Fused node0 (tiled, persistent) + degree histogram ----------------

__global__ __launch_bounds__(256, 4) void k_node0h(const float* __restrict__ x,
                                                   const float* __restrict__ emb,
                                                   const float* __restrict__ W0,
                                                   const float* __restrict__ asrc,
                                                   const float* __restrict__ adst,
                                                   const int* __restrict__ ei,
                                                   uint* __restrict__ h0p,
                                                   float2* __restrict__ as0,
                                                   float2* __restrict__ ad0,
                                                   int* __restrict__ deg) {
  int tid = threadIdx.x;
  if (blockIdx.x >= NODE0_BLOCKS) {  // histogram part
    int e = (blockIdx.x - NODE0_BLOCKS) * 256 + tid;
    if (e < N_EDGES) atomicAdd(&deg[ei[N_EDGES + e]], 1);
    return;
  }
  __shared__ float hin_s[4][4][48];  // [wave][node][k]
  int lane = tid & 63, wid = tid >> 6;
  float2 w0r[D_IN];
#pragma unroll
  for (int k = 0; k < D_IN; ++k)
    w0r[k] = make_float2(W0[k * 128 + lane], W0[k * 128 + 64 + lane]);
  float a_s0 = asrc[lane], a_s1 = asrc[64 + lane];
  float a_d0 = adst[lane], a_d1 = adst[64 + lane];

  int gw = blockIdx.x * 4 + wid;
  for (int g = gw; g < N_NODES / 4; g += NODE0_BLOCKS * 4) {
    int nb = g * 4;
#pragma unroll
    for (int j = 0; j < 4; ++j) {
      int n = nb + j;
      float t = 0.f;
      if (lane < 33) t = x[n * X_STRIDE + lane];
      int cid = (int)__shfl(t, 32, 64);
      cid = cid < 0 ? 0 : (cid >= NUM_CELLS ? NUM_CELLS - 1 : cid);  // fault guard
      if (lane >= 32 && lane < 48) t = emb[cid * CELL_DIM + (lane - 32)];
      if (lane < 48) hin_s[wid][j][lane] = t;
    }
#pragma unroll
    for (int j = 0; j < 4; ++j) {
      int n = nb + j;
      const float4* hp = (const float4*)hin_s[wid][j];
      float acc0 = 0.f, acc1 = 0.f;
#pragma unroll
      for (int k4 = 0; k4 < 12; ++k4) {
        float4 h = hp[k4];
        acc0 = fmaf(h.x, w0r[4 * k4 + 0].x, acc0); acc1 = fmaf(h.x, w0r[4 * k4 + 0].y, acc1);
        acc0 = fmaf(h.y, w0r[4 * k4 + 1].x, acc0); acc1 = fmaf(h.y, w0r[4 * k4 + 1].y, acc1);
        acc0 = fmaf(h.z, w0r[4 * k4 + 2].x, acc0); acc1 = fmaf(h.z, w0r[4 * k4 + 2].y, acc1);
        acc0 = fmaf(h.w, w0r[4 * k4 + 3].x, acc0); acc1 = fmaf(h.w, w0r[4 * k4 + 3].y, acc1);
      }
      h0p[n * 64 + lane] = f2b(acc0) | (f2b(acc1) << 16);
      float sa0 = acc0 * a_s0, sa1 = acc1 * a_s1;
      float sd0 = acc0 * a_d0, sd1 = acc1 * a_d1;
#pragma unroll
      for (int o = 32; o >= 1; o >>= 1) {
        sa0 += __shfl_xor(sa0, o, 64);
        sa1 += __shfl_xor(sa1, o, 64);
        sd0 += __shfl_xor(sd0, o, 64);
        sd1 += __shfl_xor(sd1, o, 64);
      }
      if (lane == 0) {
        as0[n] = make_float2(sa0, sa1);
        ad0[n] = make_float2(sd0, sd1);
      }
    }
  }
}

// ---------------- CSR scans ----------------

__global__ __launch_bounds__(1024) void k_scan1(const int* __restrict__ deg, int* __restrict__ off,
                                                int* __restrict__ bsum) {
  __shared__ int ws[16];
  int tid = threadIdx.x;
  int lane = tid & 63, wid = tid >> 6;
  int i = blockIdx.x * 1024 + tid;
  int v = (i < N_NODES) ? deg[i] + 1 : 0;  // +1 slot for self-loop
  int sc = v;
#pragma unroll
  for (int o = 1; o < 64; o <<= 1) {
    int t = __shfl_up(sc, o, 64);
    if (lane >= o) sc += t;
  }
  if (lane == 63) ws[wid] = sc;
  __syncthreads();
  if (tid < 16) {
    int w = ws[tid];
    int s = w;
#pragma unroll
    for (int o = 1; o < 16; o <<= 1) {
      int t = __shfl_up(s, o, 64);
      if (tid >= o) s += t;
    }
    ws[tid] = s - w;  // exclusive wave prefix
  }
  __syncthreads();
  int excl = sc - v + ws[wid];
  if (i < N_NODES) off[i] = excl;
  if (tid == 1023) bsum[blockIdx.x] = excl + v;  // block total
}

__global__ __launch_bounds__(1024) void k_scan23(int* __restrict__ off, int* __restrict__ ofs,
                                                 const int* __restrict__ bsum) {
  __shared__ int carry_s;
  int tid = threadIdx.x;
  if (tid < 64) {
    int v = (tid < SCAN_BLOCKS) ? bsum[tid] : 0;
    int s = v;
#pragma unroll
    for (int o = 1; o < 64; o <<= 1) {
      int t = __shfl_up(s, o, 64);
      if (tid >= o) s += t;
    }
    if (tid == (int)blockIdx.x) carry_s = s - v;  // exclusive prefix of this block
  }
  __syncthreads();
  int carry = carry_s;
  int i = blockIdx.x * 1024 + tid;
  if (i < N_NODES) {
    int v = off[i] + carry;
    off[i] = v;
    ofs[i] = v;
  }
  if (i == 0) off[N_NODES] = E_TOT;
}

// scatter edges into CSR slots + compute layer-0 attention weights; tail fills self-loops
__global__ __launch_bounds__(256) void k_scatter(const int* __restrict__ ei, int* __restrict__ ofs,
                                                 const int* __restrict__ off,
                                                 const float2* __restrict__ as0v,
                                                 const float2* __restrict__ ad0v,
                                                 uint2* __restrict__ ew) {
  int t = blockIdx.x * 256 + threadIdx.x;
  if (t < N_EDGES) {
    int s = ei[t], d = ei[N_EDGES + t];
    float2 a_s = as0v[s], a_d = ad0v[d];
    float w0 = __expf(lrelu(a_s.x + a_d.x));
    float w1 = __expf(lrelu(a_s.y + a_d.y));
    int p = atomicAdd(&ofs[d], 1);
    ew[p] = make_uint2((uint)s, f2b(w0) | (f2b(w1) << 16));
  } else if (t < N_EDGES + N_NODES) {
    int n = t - N_EDGES;  // self-loop record in the reserved last slot
    int slot = off[n + 1] - 1;
    float2 a_s = as0v[n], a_d = ad0v[n];
    float w0 = __expf(lrelu(a_s.x + a_d.x));
    float w1 = __expf(lrelu(a_s.y + a_d.y));
    ew[slot] = make_uint2((uint)n, f2b(w0) | (f2b(w1) << 16));
  }
}

// ---------------- Fused aggregate L0 (+LN+ELU+linear1+alpha1) — R10 known-best ----------------

__global__ __launch_bounds__(256) void k_agg0(const int* __restrict__ off,
                                              const uint2* __restrict__ ew,
                                              const uint* __restrict__ h0p,
                                              const float* __restrict__ b0,
                                              const float* __restrict__ lng,
                                              const float* __restrict__ lnb,
                                              const float* __restrict__ W1,
                                              const float* __restrict__ asrc1,
                                              const float* __restrict__ adst1,
                                              ushort* __restrict__ h1b,
                                              float* __restrict__ as1, float* __restrict__ ad1) {
  int n = blockIdx.x * 4 + (threadIdx.x >> 6);
  int lane = threadIdx.x & 63;
  float acc0 = 0.f, acc1 = 0.f, den0 = 0.f, den1 = 0.f;
  int i0 = off[n], i1 = off[n + 1];
  int i = i0;
  for (; i + 7 < i1; i += 8) {
    uint2 r[8];
    uint h[8];
#pragma unroll
    for (int j = 0; j < 8; ++j) r[j] = ew[i + j];
#pragma unroll
    for (int j = 0; j < 8; ++j) h[j] = h0p[r[j].x * 64 + lane];
#pragma unroll
    for (int j = 0; j < 8; ++j) {
      float w;
      w = b2f_lo(r[j].y); acc0 += w * b2f_lo(h[j]); den0 += w;
      w = b2f_hi(r[j].y); acc1 += w * b2f_hi(h[j]); den1 += w;
    }
  }
  for (; i + 3 < i1; i += 4) {
    uint2 r[4];
    uint h[4];
#pragma unroll
    for (int j = 0; j < 4; ++j) r[j] = ew[i + j];
#pragma unroll
    for (int j = 0; j < 4; ++j) h[j] = h0p[r[j].x * 64 + lane];
#pragma unroll
    for (int j = 0; j < 4; ++j) {
      float w;
      w = b2f_lo(r[j].y); acc0 += w * b2f_lo(h[j]); den0 += w;
      w = b2f_hi(r[j].y); acc1 += w * b2f_hi(h[j]); den1 += w;
    }
  }
  for (; i < i1; ++i) {
    uint2 r = ew[i];
    uint h = h0p[r.x * 64 + lane];
    float w;
    w = b2f_lo(r.y); acc0 += w * b2f_lo(h); den0 += w;
    w = b2f_hi(r.y); acc1 += w * b2f_hi(h); den1 += w;
  }
  float v = 0.5f * (acc0 / den0 + acc1 / den1) + b0[lane];
  // LayerNorm across the 64 channels (one wave)
  float mu = v;
#pragma unroll
  for (int o = 32; o >= 1; o >>= 1) mu += __shfl_xor(mu, o, 64);
  mu *= (1.0f / 64.0f);
  float d = v - mu;
  float vr = d * d;
#pragma unroll
  for (int o = 32; o >= 1; o >>= 1) vr += __shfl_xor(vr, o, 64);
  vr *= (1.0f / 64.0f);
  float y = d * rsqrtf(vr + 1e-5f) * lng[lane] + lnb[lane];
  // ELU
  y = y > 0.f ? y : expm1f(y);
  // linear1: h1[c] = sum_k y_k * W1[k,c]
  float h1v = 0.f;
#pragma unroll
  for (int k = 0; k < 64; ++k) {
    float yk = __shfl(y, k, 64);
    h1v += yk * W1[k * 64 + lane];
  }
  h1b[n * 64 + lane] = (ushort)f2b(h1v);
  float sa = h1v * asrc1[lane];
  float sdv = h1v * adst1[lane];
#pragma unroll
  for (int o = 32; o >= 1; o >>= 1) {
    sa += __shfl_xor(sa, o, 64);
    sdv += __shfl_xor(sdv, o, 64);
  }
  if (lane == 0) {
    as1[n] = sa;
    ad1[n] = sdv;
  }
}

// ---------------- Layer 1 aggregate -> output (weights inline; as1 is L2-resident) ----------------

__global__ __launch_bounds__(256) void k_agg1(const int* __restrict__ off,
                                              const uint2* __restrict__ ew,
                                              const ushort* __restrict__ h1b,
                                              const float* __restrict__ as1,
                                              const float* __restrict__ ad1,
                                              const float* __restrict__ b1,
                                              float* __restrict__ out) {
  int n = blockIdx.x * 4 + (threadIdx.x >> 6);
  int lane = threadIdx.x & 63;
  float adv = ad1[n];
  float acc = 0.f, den = 0.f;
  int i0 = off[n], i1 = off[n + 1];
  int i = i0;
  for (; i + 7 < i1; i += 8) {
    uint s[8];
    float a[8];
    uint h[8];
#pragma unroll
    for (int j = 0; j < 8; ++j) s[j] = ew[i + j].x;
#pragma unroll
    for (int j = 0; j < 8; ++j) a[j] = as1[s[j]];
#pragma unroll
    for (int j = 0; j < 8; ++j) h[j] = h1b[s[j] * 64 + lane];
#pragma unroll
    for (int j = 0; j < 8; ++j) {
      float w = __expf(lrelu(a[j] + adv));
      acc += w * __uint_as_float(h[j] << 16);
      den += w;
    }
  }
  for (; i + 3 < i1; i += 4) {
    uint s[4];
    float a[4];
    uint h[4];
#pragma unroll
    for (int j = 0; j < 4; ++j) s[j] = ew[i + j].x;
#pragma unroll
    for (int j = 0; j < 4; ++j) a[j] = as1[s[j]];
#pragma unroll
    for (int j = 0; j < 4; ++j) h[j] = h1b[s[j] * 64 + lane];
#pragma unroll
    for (int j = 0; j < 4; ++j) {
      float w = __expf(lrelu(a[j] + adv));
      acc += w * __uint_as_float(h[j] << 16);
      den += w;
    }
  }
  for (; i < i1; ++i) {
    uint s = ew[i].x;
    float w = __expf(lrelu(as1[s] + adv));
    acc += w * __uint_as_float((uint)h1b[s * 64 + lane] << 16);
    den += w;
  }
  out[n * 64 + lane] = acc / den + b1[lane];
}

// ---------------- host ----------------

extern "C" void kernel_launch(void* const* d_in, const int* in_sizes, int n_in,
                              void* d_out, int out_size, void* d_ws, size_t ws_size,
                              hipStream_t stream) {
  const float* x    = (const float*)d_in[0];
  const int*   ei   = (const int*)d_in[1];
  const float* emb  = (const float*)d_in[2];
  const float* W0   = (const float*)d_in[3];
  const float* as0w = (const float*)d_in[4];
  const float* ad0w = (const float*)d_in[5];
  const float* b0   = (const float*)d_in[6];
  const float* lng  = (const float*)d_in[7];
  const float* lnb  = (const float*)d_in[8];
  const float* W1   = (const float*)d_in[9];
  const float* as1w = (const float*)d_in[10];
  const float* ad1w = (const float*)d_in[11];
  const float* b1   = (const float*)d_in[12];
  float* out = (float*)d_out;

  // workspace layout (8B-aligned arrays first); total ~29 MB
  uint2* ew  = (uint2*)d_ws;                  // E_TOT {src, bf16x2 w0|w1}
  float* as0 = (float*)(ew + E_TOT);          // N*2
  float* ad0 = as0 + N_NODES * 2;             // N*2
  float* as1 = ad0 + N_NODES * 2;             // N
  float* ad1 = as1 + N_NODES;                 // N
  uint* h0p = (uint*)(ad1 + N_NODES);         // N*64 (bf16x2 packed)
  ushort* h1b = (ushort*)(h0p + N_NODES * 64);  // N*64 bf16
  int* deg  = (int*)(h1b + N_NODES * 64);     // N
  int* off  = deg + N_NODES;                  // N+1
  int* ofs  = off + N_NODES + 1;              // N
  int* bsum = ofs + N_NODES;                  // 64

  hipMemsetAsync(deg, 0, N_NODES * sizeof(int), stream);
  k_node0h<<<NODE0_BLOCKS + HIST_BLOCKS, 256, 0, stream>>>(x, emb, W0, as0w, ad0w, ei, h0p,
                                                           (float2*)as0, (float2*)ad0, deg);
  k_scan1<<<SCAN_BLOCKS, 1024, 0, stream>>>(deg, off, bsum);
  k_scan23<<<SCAN_BLOCKS, 1024, 0, stream>>>(off, ofs, bsum);
  k_scatter<<<(N_EDGES + N_NODES + 255) / 256, 256, 0, stream>>>(ei, ofs, off, (const float2*)as0,
                                                                 (const float2*)ad0, ew);
  k_agg0<<<N_NODES / 4, 256, 0, stream>>>(off, ew, h0p, b0, lng, lnb, W1, as1w, ad1w,
                                          h1b, as1, ad1);
  k_agg1<<<N_NODES / 4, 256, 0, stream>>>(off, ew, h1b, as1, ad1, b1, out);
}